// Round 2
// baseline (111.165 us; speedup 1.0000x reference)
//
#include <hip/hip_runtime.h>

#define ND 1024
#define NNE (ND*ND)

typedef __bf16 bf16x8 __attribute__((ext_vector_type(8)));
typedef float f32x4 __attribute__((ext_vector_type(4)));

__device__ __forceinline__ unsigned short f2bf(float f) {
  unsigned u = __float_as_uint(f);
  u += 0x7fffu + ((u >> 16) & 1u);
  return (unsigned short)(u >> 16);
}

__device__ __forceinline__ void gload_lds16(const void* g, void* l) {
  __builtin_amdgcn_global_load_lds(
      (const __attribute__((address_space(1))) void*)g,
      (__attribute__((address_space(3))) void*)l, 16, 0, 0);
}

// ---- convert x (256x1024 f32) -> bf16 ----
__global__ void convert_x_kernel(const float* __restrict__ x, unsigned short* __restrict__ xb) {
  int i = blockIdx.x * blockDim.x + threadIdx.x;
  float4 v = reinterpret_cast<const float4*>(x)[i];
  ushort4 o;
  o.x = f2bf(v.x); o.y = f2bf(v.y); o.z = f2bf(v.z); o.w = f2bf(v.w);
  reinterpret_cast<ushort4*>(xb)[i] = o;
}

// ---- transpose+convert psi: out[j][m][n] = bf16(psi[j][n][m]) ----
__global__ void psi_transpose_kernel(const float* __restrict__ psi, unsigned short* __restrict__ out) {
  __shared__ float t[32][33];
  int blk = blockIdx.x;
  int j  = blk >> 10;
  int tn = (blk >> 5) & 31;
  int tm = blk & 31;
  const float* src = psi + ((size_t)j << 20) + (size_t)(tn << 5) * ND + (tm << 5);
  int r  = threadIdx.x >> 3;
  int c4 = (threadIdx.x & 7) << 2;
  float4 v = *reinterpret_cast<const float4*>(src + (size_t)r * ND + c4);
  t[r][c4 + 0] = v.x; t[r][c4 + 1] = v.y; t[r][c4 + 2] = v.z; t[r][c4 + 3] = v.w;
  __syncthreads();
  ushort4 o;
  o.x = f2bf(t[c4 + 0][r]);
  o.y = f2bf(t[c4 + 1][r]);
  o.z = f2bf(t[c4 + 2][r]);
  o.w = f2bf(t[c4 + 3][r]);
  unsigned short* dst = out + ((size_t)j << 20) + (size_t)((tm << 5) + r) * ND + (tn << 5) + c4;
  *reinterpret_cast<ushort4*>(dst) = o;
}

// ---- phi order 0 ----
__global__ void phi0_kernel(const float* __restrict__ x, const float* __restrict__ lp,
                            float* __restrict__ phi) {
  int w = threadIdx.x >> 6, lane = threadIdx.x & 63;
  int row = blockIdx.x * 4 + w;
  const float* xr = x + (size_t)row * ND;
  float s = 0.f;
  for (int i = lane * 4; i < ND; i += 256) {
    float4 v = *reinterpret_cast<const float4*>(xr + i);
    float4 l = *reinterpret_cast<const float4*>(lp + i);
    s += v.x * l.x + v.y * l.y + v.z * l.z + v.w * l.w;
  }
  #pragma unroll
  for (int off = 32; off; off >>= 1) s += __shfl_xor(s, off);
  if (lane == 0) phi[row * 73] = s;
}

// ==== layer-1 GEMM (verified round-0 structure) ====
template<int BM, int BN, int LAYER>
__global__ __launch_bounds__(256)
void gemm_scat(const unsigned short* __restrict__ A,
               const unsigned short* __restrict__ BT,
               const float* __restrict__ lowpass,
               unsigned short* __restrict__ Sout,
               float* __restrict__ phi) {
  constexpr int BK = 64;
  constexpr int WM = BM / 2, WN = BN / 2;
  constexpr int MF = WM / 16, NF = WN / 16;

  __shared__ __align__(16) unsigned short Asm[BM * BK];
  __shared__ __align__(16) unsigned short Bsm[BN * BK];

  const int tid  = threadIdx.x;
  const int lane = tid & 63;
  const int w    = tid >> 6;
  const int wrow = w >> 1, wcol = w & 1;

  const int j    = blockIdx.z;
  const int row0 = blockIdx.y * BM;
  const int n0   = blockIdx.x * BN;

  const unsigned short* Bj = BT + (size_t)j * NNE;

  f32x4 acc[MF][NF] = {};

  constexpr int ACH = BM * 8;
  constexpr int BCH = BN * 8;

  for (int k0 = 0; k0 < ND; k0 += BK) {
    __syncthreads();
    #pragma unroll
    for (int p = 0; p < ACH / 256; ++p) {
      int c = p * 256 + tid;
      int r = c >> 3;
      int s = (c & 7) ^ (r & 7);
      gload_lds16(A + (size_t)(row0 + r) * ND + k0 + s * 8, Asm + c * 8);
    }
    #pragma unroll
    for (int p = 0; p < BCH / 256; ++p) {
      int c = p * 256 + tid;
      int r = c >> 3;
      int s = (c & 7) ^ (r & 7);
      gload_lds16(Bj + (size_t)(n0 + r) * ND + k0 + s * 8, Bsm + c * 8);
    }
    __syncthreads();

    #pragma unroll
    for (int kk = 0; kk < 2; ++kk) {
      bf16x8 a[MF], b[NF];
      int srd = kk * 4 + (lane >> 4);
      #pragma unroll
      for (int m = 0; m < MF; ++m) {
        int r = wrow * WM + m * 16 + (lane & 15);
        a[m] = *reinterpret_cast<const bf16x8*>(&Asm[r * 64 + ((srd ^ (r & 7)) * 8)]);
      }
      #pragma unroll
      for (int n = 0; n < NF; ++n) {
        int r = wcol * WN + n * 16 + (lane & 15);
        b[n] = *reinterpret_cast<const bf16x8*>(&Bsm[r * 64 + ((srd ^ (r & 7)) * 8)]);
      }
      #pragma unroll
      for (int m = 0; m < MF; ++m)
        #pragma unroll
        for (int n = 0; n < NF; ++n)
          acc[m][n] = __builtin_amdgcn_mfma_f32_16x16x32_bf16(a[m], b[n], acc[m][n], 0, 0, 0);
    }
  }

  float lp[NF];
  #pragma unroll
  for (int n = 0; n < NF; ++n)
    lp[n] = lowpass[n0 + wcol * WN + n * 16 + (lane & 15)];

  #pragma unroll
  for (int m = 0; m < MF; ++m) {
    #pragma unroll
    for (int r = 0; r < 4; ++r) {
      int rg = row0 + wrow * WM + m * 16 + (lane >> 4) * 4 + r;
      float psum = 0.f;
      #pragma unroll
      for (int n = 0; n < NF; ++n) {
        float v = fabsf(acc[m][n][r]);
        psum += v * lp[n];
        if (LAYER == 1) {
          int colg = n0 + wcol * WN + n * 16 + (lane & 15);
          size_t si = ((size_t)((rg >> 4) * 8 + j) * 16 + (rg & 15)) * ND + colg;
          Sout[si] = f2bf(v);
        }
      }
      psum += __shfl_xor(psum, 1);
      psum += __shfl_xor(psum, 2);
      psum += __shfl_xor(psum, 4);
      psum += __shfl_xor(psum, 8);
      if ((lane & 15) == 0) {
        int pidx;
        if (LAYER == 1) pidx = rg * 73 + 1 + j;
        else            pidx = ((rg >> 7) * 16 + (rg & 15)) * 73 + 9 + ((rg >> 4) & 7) * 8 + j;
        atomicAdd(&phi[pidx], psum);
      }
    }
  }
}

// ==== layer-2: 256x256 tile, 8-wave, 8-phase counted-vmcnt pipeline ====

template<int MH>
__device__ __forceinline__ void dsr_a(bf16x8 (&dst)[4][2], const unsigned short* base,
                                      int wrow, int l15, int l4) {
  #pragma unroll
  for (int m = 0; m < 4; ++m) {
    int r = wrow * 128 + (MH + m) * 16 + l15;
    #pragma unroll
    for (int kk = 0; kk < 2; ++kk) {
      int q = kk * 4 + l4;
      dst[m][kk] = *reinterpret_cast<const bf16x8*>(base + r * 64 + ((q ^ (r & 7)) << 3));
    }
  }
}

template<int NL>
__device__ __forceinline__ void dsr_b(bf16x8 (&dst)[2][2], const unsigned short* base,
                                      int wcol, int l15, int l4) {
  #pragma unroll
  for (int n = 0; n < 2; ++n) {
    int r = wcol * 64 + (NL + n) * 16 + l15;
    #pragma unroll
    for (int kk = 0; kk < 2; ++kk) {
      int q = kk * 4 + l4;
      dst[n][kk] = *reinterpret_cast<const bf16x8*>(base + r * 64 + ((q ^ (r & 7)) << 3));
    }
  }
}

template<int MH, int NL>
__device__ __forceinline__ void mfma_q(f32x4 (&acc)[8][4], const bf16x8 (&a)[4][2],
                                       const bf16x8 (&b)[2][2]) {
  #pragma unroll
  for (int kk = 0; kk < 2; ++kk)
    #pragma unroll
    for (int m = 0; m < 4; ++m)
      #pragma unroll
      for (int n = 0; n < 2; ++n)
        acc[MH + m][NL + n] = __builtin_amdgcn_mfma_f32_16x16x32_bf16(
            a[m][kk], b[n][kk], acc[MH + m][NL + n], 0, 0, 0);
}

// stage one full 256x64 K-tile of operand (4 x gload_lds16 per thread, 512 thr)
__device__ __forceinline__ void stage_tile(const unsigned short* __restrict__ g, int grow0,
                                           int kofs, unsigned short* l, int tid) {
  #pragma unroll
  for (int p = 0; p < 4; ++p) {
    int c = p * 512 + tid;
    int r = c >> 3;
    int s = (c & 7) ^ (r & 7);
    gload_lds16(g + (size_t)(grow0 + r) * ND + kofs + (s << 3), l + (size_t)c * 8);
  }
}

#define SBAR()  __builtin_amdgcn_s_barrier()
#define SCHED0() __builtin_amdgcn_sched_barrier(0)
#define WAIT_LGKM0() do { asm volatile("s_waitcnt lgkmcnt(0)" ::: "memory"); SCHED0(); } while (0)
#define WAIT_VM(N) do { asm volatile("s_waitcnt vmcnt(" #N ")" ::: "memory"); SCHED0(); } while (0)
#define PRIO_MFMA(stmt) do { __builtin_amdgcn_s_setprio(1); stmt; __builtin_amdgcn_s_setprio(0); SCHED0(); } while (0)

__global__ __launch_bounds__(512, 2)
void gemm_scat2(const unsigned short* __restrict__ A,
                const unsigned short* __restrict__ BT,
                const float* __restrict__ lowpass,
                float* __restrict__ phi) {
  extern __shared__ __align__(16) unsigned short smem[];
  unsigned short* As0 = smem;                 // [256][64] tile, dbuf 0
  unsigned short* As1 = smem + 16384;
  unsigned short* Bs0 = smem + 32768;
  unsigned short* Bs1 = smem + 49152;

  const int tid  = threadIdx.x;
  const int lane = tid & 63;
  const int w    = tid >> 6;          // 8 waves: 2M x 4N
  const int wrow = w >> 2, wcol = w & 3;
  const int l15  = lane & 15, l4 = lane >> 4;

  // XCD swizzle: block -> (ntile, mtile, j); each XCD serves exactly one j.
  int wg  = blockIdx.x;
  int swz = (wg & 7) * 32 + (wg >> 3);
  const int ntile = swz & 3, mtile = (swz >> 2) & 7, j = swz >> 5;
  const int row0 = mtile * 256, n0 = ntile * 256;
  const unsigned short* Bj = BT + (size_t)j * NNE;

  f32x4 acc[8][4] = {};
  bf16x8 a0e[4][2], a1e[4][2], b0e[2][2], b1e[2][2];
  bf16x8 a0o[4][2], a1o[4][2], b0o[2][2], b1o[2][2];

  // prologue: stage tiles 0 (d0) and 1 (d1); gate tile0; read Q0 regs of tile0
  stage_tile(A,  row0, 0,  As0, tid);
  stage_tile(Bj, n0,   0,  Bs0, tid);
  stage_tile(A,  row0, 64, As1, tid);
  stage_tile(Bj, n0,   64, Bs1, tid);
  WAIT_VM(8);
  SBAR();
  dsr_a<0>(a0e, As0, wrow, l15, l4);
  dsr_b<0>(b0e, Bs0, wcol, l15, l4);

  for (int i = 0; i < 8; ++i) {
    const int bk = i * 128;           // c0 = k bk, c1 = bk+64, s0 = bk+128, s1 = bk+192
    const bool st = (i < 7);

    // P1: dsr b[n2-3](c0); MFMA Q0(c0)
    dsr_b<2>(b1e, Bs0, wcol, l15, l4);
    SBAR(); WAIT_LGKM0();
    PRIO_MFMA((mfma_q<0,0>(acc, a0e, b0e)));
    SBAR();

    // P2: dsr a[m4-7](c0); MFMA Q1(c0)
    dsr_a<4>(a1e, As0, wrow, l15, l4);
    SBAR(); WAIT_LGKM0();
    PRIO_MFMA((mfma_q<0,2>(acc, a0e, b1e)));
    SBAR();

    // P3: stage s0.A -> d0; MFMA Q2(c0); gate c1 (vm4: younger = P3's 4)
    if (st) stage_tile(A, row0, bk + 128, As0, tid);
    SCHED0();
    SBAR(); WAIT_LGKM0();
    PRIO_MFMA((mfma_q<4,0>(acc, a1e, b0e)));
    if (st) { WAIT_VM(4); } else { WAIT_VM(0); }
    SBAR();

    // P4: dsr Q0(c1) from d1; stage s0.B -> d0; MFMA Q3(c0)
    dsr_a<0>(a0o, As1, wrow, l15, l4);
    dsr_b<0>(b0o, Bs1, wcol, l15, l4);
    if (st) stage_tile(Bj, n0, bk + 128, Bs0, tid);
    SCHED0();
    SBAR(); WAIT_LGKM0();
    PRIO_MFMA((mfma_q<4,2>(acc, a1e, b1e)));
    SBAR();

    // P5: dsr b[n2-3](c1); MFMA Q0(c1)
    dsr_b<2>(b1o, Bs1, wcol, l15, l4);
    SBAR(); WAIT_LGKM0();
    PRIO_MFMA((mfma_q<0,0>(acc, a0o, b0o)));
    SBAR();

    // P6: dsr a[m4-7](c1); MFMA Q1(c1)
    dsr_a<4>(a1o, As1, wrow, l15, l4);
    SBAR(); WAIT_LGKM0();
    PRIO_MFMA((mfma_q<0,2>(acc, a0o, b1o)));
    SBAR();

    // P7: stage s1.A -> d1; MFMA Q2(c1); gate s0 (= next c0)
    if (st) stage_tile(A, row0, bk + 192, As1, tid);
    SCHED0();
    SBAR(); WAIT_LGKM0();
    PRIO_MFMA((mfma_q<4,0>(acc, a1o, b0o)));
    if (st) { WAIT_VM(4); }
    SBAR();

    // P8: dsr Q0(next c0) from d0; stage s1.B -> d1; MFMA Q3(c1)
    if (st) {
      dsr_a<0>(a0e, As0, wrow, l15, l4);
      dsr_b<0>(b0e, Bs0, wcol, l15, l4);
      stage_tile(Bj, n0, bk + 192, Bs1, tid);
    }
    SCHED0();
    SBAR(); WAIT_LGKM0();
    PRIO_MFMA((mfma_q<4,2>(acc, a1o, b1o)));
    SBAR();
  }

  // epilogue: abs + lowpass dot + atomics into phi[...,9+k*8+j]
  float lp[4];
  #pragma unroll
  for (int n = 0; n < 4; ++n)
    lp[n] = lowpass[n0 + wcol * 64 + n * 16 + l15];

  #pragma unroll
  for (int m = 0; m < 8; ++m) {
    #pragma unroll
    for (int r = 0; r < 4; ++r) {
      int rg = row0 + wrow * 128 + m * 16 + l4 * 4 + r;
      float psum = 0.f;
      #pragma unroll
      for (int n = 0; n < 4; ++n)
        psum += fabsf(acc[m][n][r]) * lp[n];
      psum += __shfl_xor(psum, 1);
      psum += __shfl_xor(psum, 2);
      psum += __shfl_xor(psum, 4);
      psum += __shfl_xor(psum, 8);
      if (l15 == 0) {
        int pidx = ((rg >> 7) * 16 + (rg & 15)) * 73 + 9 + ((rg >> 4) & 7) * 8 + j;
        atomicAdd(&phi[pidx], psum);
      }
    }
  }
}

extern "C" void kernel_launch(void* const* d_in, const int* in_sizes, int n_in,
                              void* d_out, int out_size, void* d_ws, size_t ws_size,
                              hipStream_t stream) {
  (void)in_sizes; (void)n_in; (void)ws_size;
  const float* x       = (const float*)d_in[0];
  const float* psi     = (const float*)d_in[1];
  const float* lowpass = (const float*)d_in[2];
  float* phi = (float*)d_out;

  unsigned short* xb   = (unsigned short*)d_ws;                        // 512 KB
  unsigned short* psiT = (unsigned short*)((char*)d_ws + (1u << 20));  // 16 MB
  unsigned short* S1   = (unsigned short*)((char*)d_ws + (18u << 20)); // 4 MB

  hipMemsetAsync(d_out, 0, sizeof(float) * (size_t)out_size, stream);

  convert_x_kernel<<<256, 256, 0, stream>>>(x, xb);
  psi_transpose_kernel<<<8192, 256, 0, stream>>>(psi, psiT);
  phi0_kernel<<<64, 256, 0, stream>>>(x, lowpass, phi);

  // layer 1: M=256 rows, tiles 64x128 -> grid (8, 4, 8)
  gemm_scat<64, 128, 1><<<dim3(8, 4, 8), 256, 0, stream>>>(xb, psiT, lowpass, S1, phi);

  // layer 2: M=2048, 256x256 tiles, 8-phase pipeline, 128 KiB dynamic LDS
  static int attr_set = 0;
  if (!attr_set) {
    hipFuncSetAttribute((const void*)gemm_scat2,
                        hipFuncAttributeMaxDynamicSharedMemorySize, 131072);
    attr_set = 1;
  }
  gemm_scat2<<<256, 512, 131072, stream>>>(S1, psiT, lowpass, phi);
}

// Round 4
// 100.494 us; speedup vs baseline: 1.1062x; 1.1062x over previous
//
#include <hip/hip_runtime.h>

#define ND 1024
#define NNE (ND*ND)

typedef __bf16 bf16x8 __attribute__((ext_vector_type(8)));
typedef float f32x4 __attribute__((ext_vector_type(4)));

__device__ __forceinline__ unsigned short f2bf(float f) {
  unsigned u = __float_as_uint(f);
  u += 0x7fffu + ((u >> 16) & 1u);
  return (unsigned short)(u >> 16);
}

__device__ __forceinline__ void gload_lds16(const void* g, void* l) {
  __builtin_amdgcn_global_load_lds(
      (const __attribute__((address_space(1))) void*)g,
      (__attribute__((address_space(3))) void*)l, 16, 0, 0);
}

// ---- convert x (256x1024 f32) -> bf16 ----
__global__ void convert_x_kernel(const float* __restrict__ x, unsigned short* __restrict__ xb) {
  int i = blockIdx.x * blockDim.x + threadIdx.x;
  float4 v = reinterpret_cast<const float4*>(x)[i];
  ushort4 o;
  o.x = f2bf(v.x); o.y = f2bf(v.y); o.z = f2bf(v.z); o.w = f2bf(v.w);
  reinterpret_cast<ushort4*>(xb)[i] = o;
}

// ---- transpose+convert psi: out[j][m][n] = bf16(psi[j][n][m]) ----
__global__ void psi_transpose_kernel(const float* __restrict__ psi, unsigned short* __restrict__ out) {
  __shared__ float t[32][33];
  int blk = blockIdx.x;
  int j  = blk >> 10;
  int tn = (blk >> 5) & 31;
  int tm = blk & 31;
  const float* src = psi + ((size_t)j << 20) + (size_t)(tn << 5) * ND + (tm << 5);
  int r  = threadIdx.x >> 3;
  int c4 = (threadIdx.x & 7) << 2;
  float4 v = *reinterpret_cast<const float4*>(src + (size_t)r * ND + c4);
  t[r][c4 + 0] = v.x; t[r][c4 + 1] = v.y; t[r][c4 + 2] = v.z; t[r][c4 + 3] = v.w;
  __syncthreads();
  ushort4 o;
  o.x = f2bf(t[c4 + 0][r]);
  o.y = f2bf(t[c4 + 1][r]);
  o.z = f2bf(t[c4 + 2][r]);
  o.w = f2bf(t[c4 + 3][r]);
  unsigned short* dst = out + ((size_t)j << 20) + (size_t)((tm << 5) + r) * ND + (tn << 5) + c4;
  *reinterpret_cast<ushort4*>(dst) = o;
}

// ---- phi order 0 ----
__global__ void phi0_kernel(const float* __restrict__ x, const float* __restrict__ lp,
                            float* __restrict__ phi) {
  int w = threadIdx.x >> 6, lane = threadIdx.x & 63;
  int row = blockIdx.x * 4 + w;
  const float* xr = x + (size_t)row * ND;
  float s = 0.f;
  for (int i = lane * 4; i < ND; i += 256) {
    float4 v = *reinterpret_cast<const float4*>(xr + i);
    float4 l = *reinterpret_cast<const float4*>(lp + i);
    s += v.x * l.x + v.y * l.y + v.z * l.z + v.w * l.w;
  }
  #pragma unroll
  for (int off = 32; off; off >>= 1) s += __shfl_xor(s, off);
  if (lane == 0) phi[row * 73] = s;
}

// ==== layer-1 GEMM (verified round-0 structure, unchanged) ====
template<int BM, int BN, int LAYER>
__global__ __launch_bounds__(256)
void gemm_scat(const unsigned short* __restrict__ A,
               const unsigned short* __restrict__ BT,
               const float* __restrict__ lowpass,
               unsigned short* __restrict__ Sout,
               float* __restrict__ phi) {
  constexpr int BK = 64;
  constexpr int WM = BM / 2, WN = BN / 2;
  constexpr int MF = WM / 16, NF = WN / 16;

  __shared__ __align__(16) unsigned short Asm[BM * BK];
  __shared__ __align__(16) unsigned short Bsm[BN * BK];

  const int tid  = threadIdx.x;
  const int lane = tid & 63;
  const int w    = tid >> 6;
  const int wrow = w >> 1, wcol = w & 1;

  const int j    = blockIdx.z;
  const int row0 = blockIdx.y * BM;
  const int n0   = blockIdx.x * BN;

  const unsigned short* Bj = BT + (size_t)j * NNE;

  f32x4 acc[MF][NF] = {};

  constexpr int ACH = BM * 8;
  constexpr int BCH = BN * 8;

  for (int k0 = 0; k0 < ND; k0 += BK) {
    __syncthreads();
    #pragma unroll
    for (int p = 0; p < ACH / 256; ++p) {
      int c = p * 256 + tid;
      int r = c >> 3;
      int s = (c & 7) ^ (r & 7);
      gload_lds16(A + (size_t)(row0 + r) * ND + k0 + s * 8, Asm + c * 8);
    }
    #pragma unroll
    for (int p = 0; p < BCH / 256; ++p) {
      int c = p * 256 + tid;
      int r = c >> 3;
      int s = (c & 7) ^ (r & 7);
      gload_lds16(Bj + (size_t)(n0 + r) * ND + k0 + s * 8, Bsm + c * 8);
    }
    __syncthreads();

    #pragma unroll
    for (int kk = 0; kk < 2; ++kk) {
      bf16x8 a[MF], b[NF];
      int srd = kk * 4 + (lane >> 4);
      #pragma unroll
      for (int m = 0; m < MF; ++m) {
        int r = wrow * WM + m * 16 + (lane & 15);
        a[m] = *reinterpret_cast<const bf16x8*>(&Asm[r * 64 + ((srd ^ (r & 7)) * 8)]);
      }
      #pragma unroll
      for (int n = 0; n < NF; ++n) {
        int r = wcol * WN + n * 16 + (lane & 15);
        b[n] = *reinterpret_cast<const bf16x8*>(&Bsm[r * 64 + ((srd ^ (r & 7)) * 8)]);
      }
      #pragma unroll
      for (int m = 0; m < MF; ++m)
        #pragma unroll
        for (int n = 0; n < NF; ++n)
          acc[m][n] = __builtin_amdgcn_mfma_f32_16x16x32_bf16(a[m], b[n], acc[m][n], 0, 0, 0);
    }
  }

  float lp[NF];
  #pragma unroll
  for (int n = 0; n < NF; ++n)
    lp[n] = lowpass[n0 + wcol * WN + n * 16 + (lane & 15)];

  #pragma unroll
  for (int m = 0; m < MF; ++m) {
    #pragma unroll
    for (int r = 0; r < 4; ++r) {
      int rg = row0 + wrow * WM + m * 16 + (lane >> 4) * 4 + r;
      float psum = 0.f;
      #pragma unroll
      for (int n = 0; n < NF; ++n) {
        float v = fabsf(acc[m][n][r]);
        psum += v * lp[n];
        if (LAYER == 1) {
          int colg = n0 + wcol * WN + n * 16 + (lane & 15);
          size_t si = ((size_t)((rg >> 4) * 8 + j) * 16 + (rg & 15)) * ND + colg;
          Sout[si] = f2bf(v);
        }
      }
      psum += __shfl_xor(psum, 1);
      psum += __shfl_xor(psum, 2);
      psum += __shfl_xor(psum, 4);
      psum += __shfl_xor(psum, 8);
      if ((lane & 15) == 0) {
        int pidx;
        if (LAYER == 1) pidx = rg * 73 + 1 + j;
        else            pidx = ((rg >> 7) * 16 + (rg & 15)) * 73 + 9 + ((rg >> 4) & 7) * 8 + j;
        atomicAdd(&phi[pidx], psum);
      }
    }
  }
}

// ==== layer-2: 128x128 tile, 8 waves (64x32 each), 2-phase dbuf, hi occupancy ====

__device__ __forceinline__ void stage2(const unsigned short* __restrict__ A,
                                       const unsigned short* __restrict__ Bj,
                                       int row0, int n0, int k0,
                                       unsigned short* as, unsigned short* bs, int tid) {
  #pragma unroll
  for (int p = 0; p < 2; ++p) {
    int c = p * 512 + tid;
    int r = c >> 3;
    int s = (c & 7) ^ (r & 7);
    gload_lds16(A + (size_t)(row0 + r) * ND + k0 + (s << 3), as + (size_t)c * 8);
  }
  #pragma unroll
  for (int p = 0; p < 2; ++p) {
    int c = p * 512 + tid;
    int r = c >> 3;
    int s = (c & 7) ^ (r & 7);
    gload_lds16(Bj + (size_t)(n0 + r) * ND + k0 + (s << 3), bs + (size_t)c * 8);
  }
}

__device__ __forceinline__ void compute64(const unsigned short* as, const unsigned short* bs,
                                          f32x4 (&acc)[4][2],
                                          int wrow, int wcol, int l15, int l4) {
  bf16x8 a[4][2], b[2][2];
  #pragma unroll
  for (int m = 0; m < 4; ++m) {
    int r = wrow * 64 + m * 16 + l15;
    #pragma unroll
    for (int kk = 0; kk < 2; ++kk) {
      int q = kk * 4 + l4;
      a[m][kk] = *reinterpret_cast<const bf16x8*>(as + r * 64 + ((q ^ (r & 7)) << 3));
    }
  }
  #pragma unroll
  for (int n = 0; n < 2; ++n) {
    int r = wcol * 32 + n * 16 + l15;
    #pragma unroll
    for (int kk = 0; kk < 2; ++kk) {
      int q = kk * 4 + l4;
      b[n][kk] = *reinterpret_cast<const bf16x8*>(bs + r * 64 + ((q ^ (r & 7)) << 3));
    }
  }
  #pragma unroll
  for (int kk = 0; kk < 2; ++kk)
    #pragma unroll
    for (int m = 0; m < 4; ++m)
      #pragma unroll
      for (int n = 0; n < 2; ++n)
        acc[m][n] = __builtin_amdgcn_mfma_f32_16x16x32_bf16(a[m][kk], b[n][kk], acc[m][n], 0, 0, 0);
}

__global__ __launch_bounds__(512, 4)
void gemm_scat2(const unsigned short* __restrict__ A,
                const unsigned short* __restrict__ BT,
                const float* __restrict__ lowpass,
                float* __restrict__ phi) {
  __shared__ __align__(16) unsigned short As0[128 * 64];
  __shared__ __align__(16) unsigned short As1[128 * 64];
  __shared__ __align__(16) unsigned short Bs0[128 * 64];
  __shared__ __align__(16) unsigned short Bs1[128 * 64];

  const int tid  = threadIdx.x;
  const int lane = tid & 63;
  const int w    = tid >> 6;          // 8 waves: 2 rows x 4 cols
  const int wrow = w >> 2, wcol = w & 3;
  const int l15  = lane & 15, l4 = lane >> 4;

  // j = wg & 7 -> all blocks of one j land on one XCD (round-robin dispatch)
  int wg = blockIdx.x;
  const int j = wg & 7;
  const int t = wg >> 3;              // 0..127
  const int mtile = t & 15, ntile = t >> 4;
  const int row0 = mtile * 128, n0 = ntile * 128;
  const unsigned short* Bj = BT + (size_t)j * NNE;

  f32x4 acc[4][2] = {};

  stage2(A, Bj, row0, n0, 0, As0, Bs0, tid);
  __syncthreads();

  #pragma unroll 1
  for (int i = 0; i < 8; ++i) {
    int k = i * 128;
    stage2(A, Bj, row0, n0, k + 64, As1, Bs1, tid);     // prefetch odd tile
    compute64(As0, Bs0, acc, wrow, wcol, l15, l4);      // compute even tile
    __syncthreads();
    if (i < 7) stage2(A, Bj, row0, n0, k + 128, As0, Bs0, tid); // prefetch next even
    compute64(As1, Bs1, acc, wrow, wcol, l15, l4);      // compute odd tile
    __syncthreads();
  }

  // epilogue: abs + lowpass dot + atomics into phi[...,9+k*8+j]
  float lp[2];
  #pragma unroll
  for (int n = 0; n < 2; ++n)
    lp[n] = lowpass[n0 + wcol * 32 + n * 16 + l15];

  #pragma unroll
  for (int m = 0; m < 4; ++m) {
    #pragma unroll
    for (int r = 0; r < 4; ++r) {
      int rg = row0 + wrow * 64 + m * 16 + l4 * 4 + r;
      float psum = 0.f;
      #pragma unroll
      for (int n = 0; n < 2; ++n)
        psum += fabsf(acc[m][n][r]) * lp[n];
      psum += __shfl_xor(psum, 1);
      psum += __shfl_xor(psum, 2);
      psum += __shfl_xor(psum, 4);
      psum += __shfl_xor(psum, 8);
      if (l15 == 0) {
        int pidx = ((rg >> 7) * 16 + (rg & 15)) * 73 + 9 + ((rg >> 4) & 7) * 8 + j;
        atomicAdd(&phi[pidx], psum);
      }
    }
  }
}

extern "C" void kernel_launch(void* const* d_in, const int* in_sizes, int n_in,
                              void* d_out, int out_size, void* d_ws, size_t ws_size,
                              hipStream_t stream) {
  (void)in_sizes; (void)n_in; (void)ws_size;
  const float* x       = (const float*)d_in[0];
  const float* psi     = (const float*)d_in[1];
  const float* lowpass = (const float*)d_in[2];
  float* phi = (float*)d_out;

  unsigned short* xb   = (unsigned short*)d_ws;                        // 512 KB
  unsigned short* psiT = (unsigned short*)((char*)d_ws + (1u << 20));  // 16 MB
  unsigned short* S1   = (unsigned short*)((char*)d_ws + (18u << 20)); // 4 MB

  hipMemsetAsync(d_out, 0, sizeof(float) * (size_t)out_size, stream);

  convert_x_kernel<<<256, 256, 0, stream>>>(x, xb);
  psi_transpose_kernel<<<8192, 256, 0, stream>>>(psi, psiT);
  phi0_kernel<<<64, 256, 0, stream>>>(x, lowpass, phi);

  // layer 1: M=256 rows, tiles 64x128 -> grid (8, 4, 8)
  gemm_scat<64, 128, 1><<<dim3(8, 4, 8), 256, 0, stream>>>(xb, psiT, lowpass, S1, phi);

  // layer 2: M=2048, 128x128 tiles, 8 waves, 2-phase dbuf -> 1024 blocks
  gemm_scat2<<<1024, 512, 0, stream>>>(S1, psiT, lowpass, phi);
}

// Round 5
// 84.841 us; speedup vs baseline: 1.3103x; 1.1845x over previous
//
#include <hip/hip_runtime.h>

#define ND 1024
#define NNE (ND*ND)

typedef __bf16 bf16x8 __attribute__((ext_vector_type(8)));
typedef float f32x4 __attribute__((ext_vector_type(4)));

__device__ __forceinline__ unsigned short f2bf(float f) {
  unsigned u = __float_as_uint(f);
  u += 0x7fffu + ((u >> 16) & 1u);
  return (unsigned short)(u >> 16);
}

__device__ __forceinline__ void gload_lds16(const void* g, void* l) {
  __builtin_amdgcn_global_load_lds(
      (const __attribute__((address_space(1))) void*)g,
      (__attribute__((address_space(3))) void*)l, 16, 0, 0);
}

// ---- convert x (256x1024 f32) -> bf16 ----
__global__ void convert_x_kernel(const float* __restrict__ x, unsigned short* __restrict__ xb) {
  int i = blockIdx.x * blockDim.x + threadIdx.x;
  float4 v = reinterpret_cast<const float4*>(x)[i];
  ushort4 o;
  o.x = f2bf(v.x); o.y = f2bf(v.y); o.z = f2bf(v.z); o.w = f2bf(v.w);
  reinterpret_cast<ushort4*>(xb)[i] = o;
}

// ---- transpose+convert psi: out[j][m][n] = bf16(psi[j][n][m]) ----
__global__ void psi_transpose_kernel(const float* __restrict__ psi, unsigned short* __restrict__ out) {
  __shared__ float t[32][33];
  int blk = blockIdx.x;
  int j  = blk >> 10;
  int tn = (blk >> 5) & 31;
  int tm = blk & 31;
  const float* src = psi + ((size_t)j << 20) + (size_t)(tn << 5) * ND + (tm << 5);
  int r  = threadIdx.x >> 3;
  int c4 = (threadIdx.x & 7) << 2;
  float4 v = *reinterpret_cast<const float4*>(src + (size_t)r * ND + c4);
  t[r][c4 + 0] = v.x; t[r][c4 + 1] = v.y; t[r][c4 + 2] = v.z; t[r][c4 + 3] = v.w;
  __syncthreads();
  ushort4 o;
  o.x = f2bf(t[c4 + 0][r]);
  o.y = f2bf(t[c4 + 1][r]);
  o.z = f2bf(t[c4 + 2][r]);
  o.w = f2bf(t[c4 + 3][r]);
  unsigned short* dst = out + ((size_t)j << 20) + (size_t)((tm << 5) + r) * ND + (tn << 5) + c4;
  *reinterpret_cast<ushort4*>(dst) = o;
}

// ---- phi order 0 ----
__global__ void phi0_kernel(const float* __restrict__ x, const float* __restrict__ lp,
                            float* __restrict__ phi) {
  int w = threadIdx.x >> 6, lane = threadIdx.x & 63;
  int row = blockIdx.x * 4 + w;
  const float* xr = x + (size_t)row * ND;
  float s = 0.f;
  for (int i = lane * 4; i < ND; i += 256) {
    float4 v = *reinterpret_cast<const float4*>(xr + i);
    float4 l = *reinterpret_cast<const float4*>(lp + i);
    s += v.x * l.x + v.y * l.y + v.z * l.z + v.w * l.w;
  }
  #pragma unroll
  for (int off = 32; off; off >>= 1) s += __shfl_xor(s, off);
  if (lane == 0) phi[row * 73] = s;
}

// ==== layer-1 GEMM (verified round-0 structure, unchanged) ====
template<int BM, int BN, int LAYER>
__global__ __launch_bounds__(256)
void gemm_scat(const unsigned short* __restrict__ A,
               const unsigned short* __restrict__ BT,
               const float* __restrict__ lowpass,
               unsigned short* __restrict__ Sout,
               float* __restrict__ phi) {
  constexpr int BK = 64;
  constexpr int WM = BM / 2, WN = BN / 2;
  constexpr int MF = WM / 16, NF = WN / 16;

  __shared__ __align__(16) unsigned short Asm[BM * BK];
  __shared__ __align__(16) unsigned short Bsm[BN * BK];

  const int tid  = threadIdx.x;
  const int lane = tid & 63;
  const int w    = tid >> 6;
  const int wrow = w >> 1, wcol = w & 1;

  const int j    = blockIdx.z;
  const int row0 = blockIdx.y * BM;
  const int n0   = blockIdx.x * BN;

  const unsigned short* Bj = BT + (size_t)j * NNE;

  f32x4 acc[MF][NF] = {};

  constexpr int ACH = BM * 8;
  constexpr int BCH = BN * 8;

  for (int k0 = 0; k0 < ND; k0 += BK) {
    __syncthreads();
    #pragma unroll
    for (int p = 0; p < ACH / 256; ++p) {
      int c = p * 256 + tid;
      int r = c >> 3;
      int s = (c & 7) ^ (r & 7);
      gload_lds16(A + (size_t)(row0 + r) * ND + k0 + s * 8, Asm + c * 8);
    }
    #pragma unroll
    for (int p = 0; p < BCH / 256; ++p) {
      int c = p * 256 + tid;
      int r = c >> 3;
      int s = (c & 7) ^ (r & 7);
      gload_lds16(Bj + (size_t)(n0 + r) * ND + k0 + s * 8, Bsm + c * 8);
    }
    __syncthreads();

    #pragma unroll
    for (int kk = 0; kk < 2; ++kk) {
      bf16x8 a[MF], b[NF];
      int srd = kk * 4 + (lane >> 4);
      #pragma unroll
      for (int m = 0; m < MF; ++m) {
        int r = wrow * WM + m * 16 + (lane & 15);
        a[m] = *reinterpret_cast<const bf16x8*>(&Asm[r * 64 + ((srd ^ (r & 7)) * 8)]);
      }
      #pragma unroll
      for (int n = 0; n < NF; ++n) {
        int r = wcol * WN + n * 16 + (lane & 15);
        b[n] = *reinterpret_cast<const bf16x8*>(&Bsm[r * 64 + ((srd ^ (r & 7)) * 8)]);
      }
      #pragma unroll
      for (int m = 0; m < MF; ++m)
        #pragma unroll
        for (int n = 0; n < NF; ++n)
          acc[m][n] = __builtin_amdgcn_mfma_f32_16x16x32_bf16(a[m], b[n], acc[m][n], 0, 0, 0);
    }
  }

  float lp[NF];
  #pragma unroll
  for (int n = 0; n < NF; ++n)
    lp[n] = lowpass[n0 + wcol * WN + n * 16 + (lane & 15)];

  #pragma unroll
  for (int m = 0; m < MF; ++m) {
    #pragma unroll
    for (int r = 0; r < 4; ++r) {
      int rg = row0 + wrow * WM + m * 16 + (lane >> 4) * 4 + r;
      float psum = 0.f;
      #pragma unroll
      for (int n = 0; n < NF; ++n) {
        float v = fabsf(acc[m][n][r]);
        psum += v * lp[n];
        if (LAYER == 1) {
          int colg = n0 + wcol * WN + n * 16 + (lane & 15);
          size_t si = ((size_t)((rg >> 4) * 8 + j) * 16 + (rg & 15)) * ND + colg;
          Sout[si] = f2bf(v);
        }
      }
      psum += __shfl_xor(psum, 1);
      psum += __shfl_xor(psum, 2);
      psum += __shfl_xor(psum, 4);
      psum += __shfl_xor(psum, 8);
      if ((lane & 15) == 0) {
        int pidx;
        if (LAYER == 1) pidx = rg * 73 + 1 + j;
        else            pidx = ((rg >> 7) * 16 + (rg & 15)) * 73 + 9 + ((rg >> 4) & 7) * 8 + j;
        atomicAdd(&phi[pidx], psum);
      }
    }
  }
}

// ==== layer-2: 256x256 tile, 8 waves (128x64 each), 4-phase K-tile pipeline ====

template<int MH>
__device__ __forceinline__ void dsr_a(bf16x8 (&dst)[4][2], const unsigned short* base,
                                      int wrow, int l15, int l4) {
  #pragma unroll
  for (int m = 0; m < 4; ++m) {
    int r = wrow * 128 + (MH + m) * 16 + l15;
    #pragma unroll
    for (int kk = 0; kk < 2; ++kk) {
      int q = kk * 4 + l4;
      dst[m][kk] = *reinterpret_cast<const bf16x8*>(base + r * 64 + ((q ^ (r & 7)) << 3));
    }
  }
}

template<int NL>
__device__ __forceinline__ void dsr_b(bf16x8 (&dst)[2][2], const unsigned short* base,
                                      int wcol, int l15, int l4) {
  #pragma unroll
  for (int n = 0; n < 2; ++n) {
    int r = wcol * 64 + (NL + n) * 16 + l15;
    #pragma unroll
    for (int kk = 0; kk < 2; ++kk) {
      int q = kk * 4 + l4;
      dst[n][kk] = *reinterpret_cast<const bf16x8*>(base + r * 64 + ((q ^ (r & 7)) << 3));
    }
  }
}

template<int MH, int NL>
__device__ __forceinline__ void mfma_q(f32x4 (&acc)[8][4], const bf16x8 (&a)[4][2],
                                       const bf16x8 (&b)[2][2]) {
  #pragma unroll
  for (int kk = 0; kk < 2; ++kk)
    #pragma unroll
    for (int m = 0; m < 4; ++m)
      #pragma unroll
      for (int n = 0; n < 2; ++n)
        acc[MH + m][NL + n] = __builtin_amdgcn_mfma_f32_16x16x32_bf16(
            a[m][kk], b[n][kk], acc[MH + m][NL + n], 0, 0, 0);
}

// stage one full 256x64 K-tile of one operand (4 x gload_lds16 per thread, 512 thr)
__device__ __forceinline__ void stage_tile(const unsigned short* __restrict__ g, int grow0,
                                           int kofs, unsigned short* l, int tid) {
  #pragma unroll
  for (int p = 0; p < 4; ++p) {
    int c = p * 512 + tid;
    int r = c >> 3;
    int s = (c & 7) ^ (r & 7);
    gload_lds16(g + (size_t)(grow0 + r) * ND + kofs + (s << 3), l + (size_t)c * 8);
  }
}

#define SBAR()  __builtin_amdgcn_s_barrier()
#define SCHED0() __builtin_amdgcn_sched_barrier(0)
#define WAIT_LGKM0() do { asm volatile("s_waitcnt lgkmcnt(0)" ::: "memory"); SCHED0(); } while (0)
#define WAIT_VM0() do { asm volatile("s_waitcnt vmcnt(0)" ::: "memory"); SCHED0(); } while (0)
#define PRIO_MFMA(stmt) do { __builtin_amdgcn_s_setprio(1); stmt; __builtin_amdgcn_s_setprio(0); SCHED0(); } while (0)

// one K-tile (BK=64): 4 phases, ONE live fragment set (aX reused, bL+bH held)
__device__ __forceinline__ void ktile4(
    f32x4 (&acc)[8][4], bf16x8 (&aX)[4][2], bf16x8 (&bL)[2][2], bf16x8 (&bH)[2][2],
    const unsigned short* Ac, const unsigned short* Bc,
    bool st, int knext, unsigned short* An, unsigned short* Bn,
    const unsigned short* __restrict__ A, const unsigned short* __restrict__ Bj,
    int row0, int n0, int tid, int wrow, int wcol, int l15, int l4) {
  // P0: dsr aLo + bLo (cur); stage next A; MFMA Q(0,0)
  dsr_a<0>(aX, Ac, wrow, l15, l4);
  dsr_b<0>(bL, Bc, wcol, l15, l4);
  if (st) stage_tile(A, row0, knext, An, tid);
  SCHED0();
  SBAR(); WAIT_LGKM0();
  PRIO_MFMA((mfma_q<0,0>(acc, aX, bL)));
  SBAR();
  // P1: dsr bHi (cur); stage next B; MFMA Q(0,2)
  dsr_b<2>(bH, Bc, wcol, l15, l4);
  if (st) stage_tile(Bj, n0, knext, Bn, tid);
  SCHED0();
  SBAR(); WAIT_LGKM0();
  PRIO_MFMA((mfma_q<0,2>(acc, aX, bH)));
  SBAR();
  // P2: dsr aHi (cur, overwrite aX); MFMA Q(4,0)
  dsr_a<4>(aX, Ac, wrow, l15, l4);
  SBAR(); WAIT_LGKM0();
  PRIO_MFMA((mfma_q<4,0>(acc, aX, bL)));
  SBAR();
  // P3: MFMA Q(4,2); gate next tile's loads (issued >=2 phases ago)
  PRIO_MFMA((mfma_q<4,2>(acc, aX, bH)));
  WAIT_VM0();
  SBAR();
}

__global__ __launch_bounds__(512, 2)
void gemm_scat2(const unsigned short* __restrict__ A,
                const unsigned short* __restrict__ BT,
                const float* __restrict__ lowpass,
                float* __restrict__ phi) {
  extern __shared__ __align__(16) unsigned short smem[];
  unsigned short* As0 = smem;                 // [256][64] bf16, 32 KB each
  unsigned short* As1 = smem + 16384;
  unsigned short* Bs0 = smem + 32768;
  unsigned short* Bs1 = smem + 49152;

  const int tid  = threadIdx.x;
  const int lane = tid & 63;
  const int w    = tid >> 6;          // 8 waves: 2M x 4N
  const int wrow = w >> 2, wcol = w & 3;
  const int l15  = lane & 15, l4 = lane >> 4;

  // 256 blocks total: j = wg & 7 pins each psi^T[j] (2 MB) to one XCD's L2.
  int wg = blockIdx.x;
  const int j = wg & 7;
  const int t = wg >> 3;              // 0..31
  const int mtile = t & 7, ntile = t >> 3;
  const int row0 = mtile * 256, n0 = ntile * 256;
  const unsigned short* Bj = BT + (size_t)j * NNE;

  f32x4 acc[8][4] = {};
  bf16x8 aX[4][2], bL[2][2], bH[2][2];

  stage_tile(A,  row0, 0, As0, tid);
  stage_tile(Bj, n0,   0, Bs0, tid);
  WAIT_VM0();
  SBAR();

  #pragma unroll 1
  for (int i = 0; i < 8; ++i) {
    int k = i * 128;
    // even K-tile: read buf0, stage k+64 -> buf1
    ktile4(acc, aX, bL, bH, As0, Bs0, true, k + 64, As1, Bs1,
           A, Bj, row0, n0, tid, wrow, wcol, l15, l4);
    // odd K-tile: read buf1, stage k+128 -> buf0
    ktile4(acc, aX, bL, bH, As1, Bs1, (i < 7), k + 128, As0, Bs0,
           A, Bj, row0, n0, tid, wrow, wcol, l15, l4);
  }

  // epilogue: abs + lowpass dot + atomics into phi[...,9+k*8+j]
  float lp[4];
  #pragma unroll
  for (int n = 0; n < 4; ++n)
    lp[n] = lowpass[n0 + wcol * 64 + n * 16 + l15];

  #pragma unroll
  for (int m = 0; m < 8; ++m) {
    #pragma unroll
    for (int r = 0; r < 4; ++r) {
      int rg = row0 + wrow * 128 + m * 16 + l4 * 4 + r;
      float psum = 0.f;
      #pragma unroll
      for (int n = 0; n < 4; ++n)
        psum += fabsf(acc[m][n][r]) * lp[n];
      psum += __shfl_xor(psum, 1);
      psum += __shfl_xor(psum, 2);
      psum += __shfl_xor(psum, 4);
      psum += __shfl_xor(psum, 8);
      if (l15 == 0) {
        int pidx = ((rg >> 7) * 16 + (rg & 15)) * 73 + 9 + ((rg >> 4) & 7) * 8 + j;
        atomicAdd(&phi[pidx], psum);
      }
    }
  }
}

extern "C" void kernel_launch(void* const* d_in, const int* in_sizes, int n_in,
                              void* d_out, int out_size, void* d_ws, size_t ws_size,
                              hipStream_t stream) {
  (void)in_sizes; (void)n_in; (void)ws_size;
  const float* x       = (const float*)d_in[0];
  const float* psi     = (const float*)d_in[1];
  const float* lowpass = (const float*)d_in[2];
  float* phi = (float*)d_out;

  unsigned short* xb   = (unsigned short*)d_ws;                        // 512 KB
  unsigned short* psiT = (unsigned short*)((char*)d_ws + (1u << 20));  // 16 MB
  unsigned short* S1   = (unsigned short*)((char*)d_ws + (18u << 20)); // 4 MB

  hipMemsetAsync(d_out, 0, sizeof(float) * (size_t)out_size, stream);

  convert_x_kernel<<<256, 256, 0, stream>>>(x, xb);
  psi_transpose_kernel<<<8192, 256, 0, stream>>>(psi, psiT);
  phi0_kernel<<<64, 256, 0, stream>>>(x, lowpass, phi);

  // layer 1: M=256 rows, tiles 64x128 -> grid (8, 4, 8)
  gemm_scat<64, 128, 1><<<dim3(8, 4, 8), 256, 0, stream>>>(xb, psiT, lowpass, S1, phi);

  // layer 2: M=2048, 256x256 tiles, 4-phase K-loop, 128 KiB dynamic LDS, 256 blocks
  static int attr_set = 0;
  if (!attr_set) {
    hipFuncSetAttribute((const void*)gemm_scat2,
                        hipFuncAttributeMaxDynamicSharedMemorySize, 131072);
    attr_set = 1;
  }
  gemm_scat2<<<256, 512, 131072, stream>>>(S1, psiT, lowpass, phi);
}

// Round 6
// 83.672 us; speedup vs baseline: 1.3286x; 1.0140x over previous
//
#include <hip/hip_runtime.h>

#define ND 1024
#define NNE (ND*ND)

typedef __bf16 bf16x8 __attribute__((ext_vector_type(8)));
typedef float f32x4 __attribute__((ext_vector_type(4)));

__device__ __forceinline__ unsigned short f2bf(float f) {
  unsigned u = __float_as_uint(f);
  u += 0x7fffu + ((u >> 16) & 1u);
  return (unsigned short)(u >> 16);
}

__device__ __forceinline__ void gload_lds16(const void* g, void* l) {
  __builtin_amdgcn_global_load_lds(
      (const __attribute__((address_space(1))) void*)g,
      (__attribute__((address_space(3))) void*)l, 16, 0, 0);
}

// ---- fused: convert x row -> bf16, and phi[b,f,0] = x . lowpass ----
__global__ void convert_phi0_kernel(const float* __restrict__ x, const float* __restrict__ lp,
                                    unsigned short* __restrict__ xb, float* __restrict__ phi) {
  __shared__ float ws[4];
  int row = blockIdx.x;            // 256 rows
  int t   = threadIdx.x;           // 256 threads, one float4 each
  float4 v = reinterpret_cast<const float4*>(x + (size_t)row * ND)[t];
  float4 l = reinterpret_cast<const float4*>(lp)[t];
  ushort4 o;
  o.x = f2bf(v.x); o.y = f2bf(v.y); o.z = f2bf(v.z); o.w = f2bf(v.w);
  reinterpret_cast<ushort4*>(xb + (size_t)row * ND)[t] = o;
  float s = v.x * l.x + v.y * l.y + v.z * l.z + v.w * l.w;
  #pragma unroll
  for (int off = 32; off; off >>= 1) s += __shfl_xor(s, off);
  if ((t & 63) == 0) ws[t >> 6] = s;
  __syncthreads();
  if (t == 0) phi[row * 73] = ws[0] + ws[1] + ws[2] + ws[3];
}

// ---- transpose+convert psi: out[j][m][n] = bf16(psi[j][n][m]) ----
__global__ void psi_transpose_kernel(const float* __restrict__ psi, unsigned short* __restrict__ out) {
  __shared__ float t[32][33];
  int blk = blockIdx.x;
  int j  = blk >> 10;
  int tn = (blk >> 5) & 31;
  int tm = blk & 31;
  const float* src = psi + ((size_t)j << 20) + (size_t)(tn << 5) * ND + (tm << 5);
  int r  = threadIdx.x >> 3;
  int c4 = (threadIdx.x & 7) << 2;
  float4 v = *reinterpret_cast<const float4*>(src + (size_t)r * ND + c4);
  t[r][c4 + 0] = v.x; t[r][c4 + 1] = v.y; t[r][c4 + 2] = v.z; t[r][c4 + 3] = v.w;
  __syncthreads();
  ushort4 o;
  o.x = f2bf(t[c4 + 0][r]);
  o.y = f2bf(t[c4 + 1][r]);
  o.z = f2bf(t[c4 + 2][r]);
  o.w = f2bf(t[c4 + 3][r]);
  unsigned short* dst = out + ((size_t)j << 20) + (size_t)((tm << 5) + r) * ND + (tn << 5) + c4;
  *reinterpret_cast<ushort4*>(dst) = o;
}

// ==== layer-1 GEMM (verified round-0 structure, unchanged) ====
template<int BM, int BN, int LAYER>
__global__ __launch_bounds__(256)
void gemm_scat(const unsigned short* __restrict__ A,
               const unsigned short* __restrict__ BT,
               const float* __restrict__ lowpass,
               unsigned short* __restrict__ Sout,
               float* __restrict__ phi) {
  constexpr int BK = 64;
  constexpr int WM = BM / 2, WN = BN / 2;
  constexpr int MF = WM / 16, NF = WN / 16;

  __shared__ __align__(16) unsigned short Asm[BM * BK];
  __shared__ __align__(16) unsigned short Bsm[BN * BK];

  const int tid  = threadIdx.x;
  const int lane = tid & 63;
  const int w    = tid >> 6;
  const int wrow = w >> 1, wcol = w & 1;

  const int j    = blockIdx.z;
  const int row0 = blockIdx.y * BM;
  const int n0   = blockIdx.x * BN;

  const unsigned short* Bj = BT + (size_t)j * NNE;

  f32x4 acc[MF][NF] = {};

  constexpr int ACH = BM * 8;
  constexpr int BCH = BN * 8;

  for (int k0 = 0; k0 < ND; k0 += BK) {
    __syncthreads();
    #pragma unroll
    for (int p = 0; p < ACH / 256; ++p) {
      int c = p * 256 + tid;
      int r = c >> 3;
      int s = (c & 7) ^ (r & 7);
      gload_lds16(A + (size_t)(row0 + r) * ND + k0 + s * 8, Asm + c * 8);
    }
    #pragma unroll
    for (int p = 0; p < BCH / 256; ++p) {
      int c = p * 256 + tid;
      int r = c >> 3;
      int s = (c & 7) ^ (r & 7);
      gload_lds16(Bj + (size_t)(n0 + r) * ND + k0 + s * 8, Bsm + c * 8);
    }
    __syncthreads();

    #pragma unroll
    for (int kk = 0; kk < 2; ++kk) {
      bf16x8 a[MF], b[NF];
      int srd = kk * 4 + (lane >> 4);
      #pragma unroll
      for (int m = 0; m < MF; ++m) {
        int r = wrow * WM + m * 16 + (lane & 15);
        a[m] = *reinterpret_cast<const bf16x8*>(&Asm[r * 64 + ((srd ^ (r & 7)) * 8)]);
      }
      #pragma unroll
      for (int n = 0; n < NF; ++n) {
        int r = wcol * WN + n * 16 + (lane & 15);
        b[n] = *reinterpret_cast<const bf16x8*>(&Bsm[r * 64 + ((srd ^ (r & 7)) * 8)]);
      }
      #pragma unroll
      for (int m = 0; m < MF; ++m)
        #pragma unroll
        for (int n = 0; n < NF; ++n)
          acc[m][n] = __builtin_amdgcn_mfma_f32_16x16x32_bf16(a[m], b[n], acc[m][n], 0, 0, 0);
    }
  }

  float lp[NF];
  #pragma unroll
  for (int n = 0; n < NF; ++n)
    lp[n] = lowpass[n0 + wcol * WN + n * 16 + (lane & 15)];

  #pragma unroll
  for (int m = 0; m < MF; ++m) {
    #pragma unroll
    for (int r = 0; r < 4; ++r) {
      int rg = row0 + wrow * WM + m * 16 + (lane >> 4) * 4 + r;
      float psum = 0.f;
      #pragma unroll
      for (int n = 0; n < NF; ++n) {
        float v = fabsf(acc[m][n][r]);
        psum += v * lp[n];
        if (LAYER == 1) {
          int colg = n0 + wcol * WN + n * 16 + (lane & 15);
          size_t si = ((size_t)((rg >> 4) * 8 + j) * 16 + (rg & 15)) * ND + colg;
          Sout[si] = f2bf(v);
        }
      }
      psum += __shfl_xor(psum, 1);
      psum += __shfl_xor(psum, 2);
      psum += __shfl_xor(psum, 4);
      psum += __shfl_xor(psum, 8);
      if ((lane & 15) == 0) {
        int pidx;
        if (LAYER == 1) pidx = rg * 73 + 1 + j;
        else            pidx = ((rg >> 7) * 16 + (rg & 15)) * 73 + 9 + ((rg >> 4) & 7) * 8 + j;
        atomicAdd(&phi[pidx], psum);
      }
    }
  }
}

// ==== layer-2: 256x256 tile, 8 waves (128x64), 2-phase K-tile, counted vmcnt ====

template<int MH>
__device__ __forceinline__ void dsr_a(bf16x8 (&dst)[4][2], const unsigned short* base,
                                      int wrow, int l15, int l4) {
  #pragma unroll
  for (int m = 0; m < 4; ++m) {
    int r = wrow * 128 + (MH + m) * 16 + l15;
    #pragma unroll
    for (int kk = 0; kk < 2; ++kk) {
      int q = kk * 4 + l4;
      dst[m][kk] = *reinterpret_cast<const bf16x8*>(base + r * 64 + ((q ^ (r & 7)) << 3));
    }
  }
}

template<int NL>
__device__ __forceinline__ void dsr_b(bf16x8 (&dst)[2][2], const unsigned short* base,
                                      int wcol, int l15, int l4) {
  #pragma unroll
  for (int n = 0; n < 2; ++n) {
    int r = wcol * 64 + (NL + n) * 16 + l15;
    #pragma unroll
    for (int kk = 0; kk < 2; ++kk) {
      int q = kk * 4 + l4;
      dst[n][kk] = *reinterpret_cast<const bf16x8*>(base + r * 64 + ((q ^ (r & 7)) << 3));
    }
  }
}

template<int MH, int NL>
__device__ __forceinline__ void mfma_q(f32x4 (&acc)[8][4], const bf16x8 (&a)[4][2],
                                       const bf16x8 (&b)[2][2]) {
  #pragma unroll
  for (int kk = 0; kk < 2; ++kk)
    #pragma unroll
    for (int m = 0; m < 4; ++m)
      #pragma unroll
      for (int n = 0; n < 2; ++n)
        acc[MH + m][NL + n] = __builtin_amdgcn_mfma_f32_16x16x32_bf16(
            a[m][kk], b[n][kk], acc[MH + m][NL + n], 0, 0, 0);
}

// stage one full 256x64 K-tile of one operand (4 x gload_lds16 per thread, 512 thr)
__device__ __forceinline__ void stage_tile(const unsigned short* __restrict__ g, int grow0,
                                           int kofs, unsigned short* l, int tid) {
  #pragma unroll
  for (int p = 0; p < 4; ++p) {
    int c = p * 512 + tid;
    int r = c >> 3;
    int s = (c & 7) ^ (r & 7);
    gload_lds16(g + (size_t)(grow0 + r) * ND + kofs + (s << 3), l + (size_t)c * 8);
  }
}

#define SBAR()  __builtin_amdgcn_s_barrier()
#define SCHED0() __builtin_amdgcn_sched_barrier(0)
#define WAIT_LGKM0() do { asm volatile("s_waitcnt lgkmcnt(0)" ::: "memory"); SCHED0(); } while (0)
#define WAIT_VM(N) do { asm volatile("s_waitcnt vmcnt(" #N ")" ::: "memory"); SCHED0(); } while (0)

__global__ __launch_bounds__(512, 2)
void gemm_scat2(const unsigned short* __restrict__ A,
                const unsigned short* __restrict__ BT,
                const float* __restrict__ lowpass,
                float* __restrict__ phi) {
  extern __shared__ __align__(16) unsigned short smem[];
  unsigned short* As0 = smem;                 // [256][64] bf16, 32 KB each
  unsigned short* As1 = smem + 16384;
  unsigned short* Bs0 = smem + 32768;
  unsigned short* Bs1 = smem + 49152;

  const int tid  = threadIdx.x;
  const int lane = tid & 63;
  const int w    = tid >> 6;          // 8 waves: 2M x 4N
  const int wrow = w >> 2, wcol = w & 3;
  const int l15  = lane & 15, l4 = lane >> 4;

  // 256 blocks total: j = wg & 7 pins each psi^T[j] (2 MB) to one XCD's L2.
  int wg = blockIdx.x;
  const int j = wg & 7;
  const int t = wg >> 3;              // 0..31
  const int mtile = t & 7, ntile = t >> 3;
  const int row0 = mtile * 256, n0 = ntile * 256;
  const unsigned short* Bj = BT + (size_t)j * NNE;

  f32x4 acc[8][4] = {};
  bf16x8 aX[4][2], bL[2][2], bH[2][2];

  // prologue: stage K-tiles 0 and 1; gate tile0 only (tile1 stays in flight)
  stage_tile(A,  row0, 0,  As0, tid);
  stage_tile(Bj, n0,   0,  Bs0, tid);
  stage_tile(A,  row0, 64, As1, tid);
  stage_tile(Bj, n0,   64, Bs1, tid);
  WAIT_VM(8);
  SBAR();

  #pragma unroll 1
  for (int i = 0; i < 16; ++i) {
    unsigned short* Ac = (i & 1) ? As1 : As0;
    unsigned short* Bc = (i & 1) ? Bs1 : Bs0;
    const bool st = (i < 14);
    const int knext = (i + 2) * 64;

    // P0: dsr aLo + bLo + bHi (cur); MFMA Q(0,0)+Q(0,2)
    dsr_a<0>(aX, Ac, wrow, l15, l4);
    dsr_b<0>(bL, Bc, wcol, l15, l4);
    dsr_b<2>(bH, Bc, wcol, l15, l4);
    SBAR(); WAIT_LGKM0();
    __builtin_amdgcn_s_setprio(1);
    mfma_q<0,0>(acc, aX, bL);
    mfma_q<0,2>(acc, aX, bH);
    __builtin_amdgcn_s_setprio(0);
    SCHED0();
    SBAR();

    // P1: dsr aHi (cur); all reads of cur now done -> stage tile i+2 into cur;
    //     MFMA Q(4,0)+Q(4,2); counted gate: tile i+2's 8 loads stay in flight,
    //     everything older (tile i+1) certified complete.
    dsr_a<4>(aX, Ac, wrow, l15, l4);
    WAIT_LGKM0();
    SBAR();
    if (st) {
      stage_tile(A,  row0, knext, Ac, tid);
      stage_tile(Bj, n0,   knext, Bc, tid);
    }
    SCHED0();
    __builtin_amdgcn_s_setprio(1);
    mfma_q<4,0>(acc, aX, bL);
    mfma_q<4,2>(acc, aX, bH);
    __builtin_amdgcn_s_setprio(0);
    SCHED0();
    if (st) { WAIT_VM(8); } else { WAIT_VM(0); }
    SBAR();
  }

  // epilogue: abs + lowpass dot + atomics into phi[...,9+k*8+j]
  float lp[4];
  #pragma unroll
  for (int n = 0; n < 4; ++n)
    lp[n] = lowpass[n0 + wcol * 64 + n * 16 + l15];

  #pragma unroll
  for (int m = 0; m < 8; ++m) {
    #pragma unroll
    for (int r = 0; r < 4; ++r) {
      int rg = row0 + wrow * 128 + m * 16 + l4 * 4 + r;
      float psum = 0.f;
      #pragma unroll
      for (int n = 0; n < 4; ++n)
        psum += fabsf(acc[m][n][r]) * lp[n];
      psum += __shfl_xor(psum, 1);
      psum += __shfl_xor(psum, 2);
      psum += __shfl_xor(psum, 4);
      psum += __shfl_xor(psum, 8);
      if (l15 == 0) {
        int pidx = ((rg >> 7) * 16 + (rg & 15)) * 73 + 9 + ((rg >> 4) & 7) * 8 + j;
        atomicAdd(&phi[pidx], psum);
      }
    }
  }
}

extern "C" void kernel_launch(void* const* d_in, const int* in_sizes, int n_in,
                              void* d_out, int out_size, void* d_ws, size_t ws_size,
                              hipStream_t stream) {
  (void)in_sizes; (void)n_in; (void)ws_size;
  const float* x       = (const float*)d_in[0];
  const float* psi     = (const float*)d_in[1];
  const float* lowpass = (const float*)d_in[2];
  float* phi = (float*)d_out;

  unsigned short* xb   = (unsigned short*)d_ws;                        // 512 KB
  unsigned short* psiT = (unsigned short*)((char*)d_ws + (1u << 20));  // 16 MB
  unsigned short* S1   = (unsigned short*)((char*)d_ws + (18u << 20)); // 4 MB

  hipMemsetAsync(d_out, 0, sizeof(float) * (size_t)out_size, stream);

  convert_phi0_kernel<<<256, 256, 0, stream>>>(x, lowpass, xb, phi);
  psi_transpose_kernel<<<8192, 256, 0, stream>>>(psi, psiT);

  // layer 1: M=256 rows, tiles 64x128 -> grid (8, 4, 8)
  gemm_scat<64, 128, 1><<<dim3(8, 4, 8), 256, 0, stream>>>(xb, psiT, lowpass, S1, phi);

  // layer 2: M=2048, 256x256 tiles, 2-phase K-loop + counted vmcnt, 128 KiB LDS
  static int attr_set = 0;
  if (!attr_set) {
    hipFuncSetAttribute((const void*)gemm_scat2,
                        hipFuncAttributeMaxDynamicSharedMemorySize, 131072);
    attr_set = 1;
  }
  gemm_scat2<<<256, 512, 131072, stream>>>(S1, psiT, lowpass, phi);
}

// Round 9
// 83.249 us; speedup vs baseline: 1.3353x; 1.0051x over previous
//
#include <hip/hip_runtime.h>

#define ND 1024
#define NNE (ND*ND)

typedef __bf16 bf16x8 __attribute__((ext_vector_type(8)));
typedef float f32x4 __attribute__((ext_vector_type(4)));

__device__ __forceinline__ unsigned short f2bf(float f) {
  unsigned u = __float_as_uint(f);
  u += 0x7fffu + ((u >> 16) & 1u);
  return (unsigned short)(u >> 16);
}

__device__ __forceinline__ void gload_lds16(const void* g, void* l) {
  __builtin_amdgcn_global_load_lds(
      (const __attribute__((address_space(1))) void*)g,
      (__attribute__((address_space(3))) void*)l, 16, 0, 0);
}

// ---- fused: convert x row -> bf16, and phi[b,f,0] = x . lowpass ----
__global__ void convert_phi0_kernel(const float* __restrict__ x, const float* __restrict__ lp,
                                    unsigned short* __restrict__ xb, float* __restrict__ phi) {
  __shared__ float ws[4];
  int row = blockIdx.x;            // 256 rows
  int t   = threadIdx.x;           // 256 threads, one float4 each
  float4 v = reinterpret_cast<const float4*>(x + (size_t)row * ND)[t];
  float4 l = reinterpret_cast<const float4*>(lp)[t];
  ushort4 o;
  o.x = f2bf(v.x); o.y = f2bf(v.y); o.z = f2bf(v.z); o.w = f2bf(v.w);
  reinterpret_cast<ushort4*>(xb + (size_t)row * ND)[t] = o;
  float s = v.x * l.x + v.y * l.y + v.z * l.z + v.w * l.w;
  #pragma unroll
  for (int off = 32; off; off >>= 1) s += __shfl_xor(s, off);
  if ((t & 63) == 0) ws[t >> 6] = s;
  __syncthreads();
  if (t == 0) phi[row * 73] = ws[0] + ws[1] + ws[2] + ws[3];
}

// ---- transpose+convert psi: out[j][m][n] = bf16(psi[j][n][m]) ----
__global__ void psi_transpose_kernel(const float* __restrict__ psi, unsigned short* __restrict__ out) {
  __shared__ float t[32][33];
  int blk = blockIdx.x;
  int j  = blk >> 10;
  int tn = (blk >> 5) & 31;
  int tm = blk & 31;
  const float* src = psi + ((size_t)j << 20) + (size_t)(tn << 5) * ND + (tm << 5);
  int r  = threadIdx.x >> 3;
  int c4 = (threadIdx.x & 7) << 2;
  float4 v = *reinterpret_cast<const float4*>(src + (size_t)r * ND + c4);
  t[r][c4 + 0] = v.x; t[r][c4 + 1] = v.y; t[r][c4 + 2] = v.z; t[r][c4 + 3] = v.w;
  __syncthreads();
  ushort4 o;
  o.x = f2bf(t[c4 + 0][r]);
  o.y = f2bf(t[c4 + 1][r]);
  o.z = f2bf(t[c4 + 2][r]);
  o.w = f2bf(t[c4 + 3][r]);
  unsigned short* dst = out + ((size_t)j << 20) + (size_t)((tm << 5) + r) * ND + (tn << 5) + c4;
  *reinterpret_cast<ushort4*>(dst) = o;
}

// ==== layer-1 GEMM (verified round-0 structure, unchanged) ====
template<int BM, int BN, int LAYER>
__global__ __launch_bounds__(256)
void gemm_scat(const unsigned short* __restrict__ A,
               const unsigned short* __restrict__ BT,
               const float* __restrict__ lowpass,
               unsigned short* __restrict__ Sout,
               float* __restrict__ phi) {
  constexpr int BK = 64;
  constexpr int WM = BM / 2, WN = BN / 2;
  constexpr int MF = WM / 16, NF = WN / 16;

  __shared__ __align__(16) unsigned short Asm[BM * BK];
  __shared__ __align__(16) unsigned short Bsm[BN * BK];

  const int tid  = threadIdx.x;
  const int lane = tid & 63;
  const int w    = tid >> 6;
  const int wrow = w >> 1, wcol = w & 1;

  const int j    = blockIdx.z;
  const int row0 = blockIdx.y * BM;
  const int n0   = blockIdx.x * BN;

  const unsigned short* Bj = BT + (size_t)j * NNE;

  f32x4 acc[MF][NF] = {};

  constexpr int ACH = BM * 8;
  constexpr int BCH = BN * 8;

  for (int k0 = 0; k0 < ND; k0 += BK) {
    __syncthreads();
    #pragma unroll
    for (int p = 0; p < ACH / 256; ++p) {
      int c = p * 256 + tid;
      int r = c >> 3;
      int s = (c & 7) ^ (r & 7);
      gload_lds16(A + (size_t)(row0 + r) * ND + k0 + s * 8, Asm + c * 8);
    }
    #pragma unroll
    for (int p = 0; p < BCH / 256; ++p) {
      int c = p * 256 + tid;
      int r = c >> 3;
      int s = (c & 7) ^ (r & 7);
      gload_lds16(Bj + (size_t)(n0 + r) * ND + k0 + s * 8, Bsm + c * 8);
    }
    __syncthreads();

    #pragma unroll
    for (int kk = 0; kk < 2; ++kk) {
      bf16x8 a[MF], b[NF];
      int srd = kk * 4 + (lane >> 4);
      #pragma unroll
      for (int m = 0; m < MF; ++m) {
        int r = wrow * WM + m * 16 + (lane & 15);
        a[m] = *reinterpret_cast<const bf16x8*>(&Asm[r * 64 + ((srd ^ (r & 7)) * 8)]);
      }
      #pragma unroll
      for (int n = 0; n < NF; ++n) {
        int r = wcol * WN + n * 16 + (lane & 15);
        b[n] = *reinterpret_cast<const bf16x8*>(&Bsm[r * 64 + ((srd ^ (r & 7)) * 8)]);
      }
      #pragma unroll
      for (int m = 0; m < MF; ++m)
        #pragma unroll
        for (int n = 0; n < NF; ++n)
          acc[m][n] = __builtin_amdgcn_mfma_f32_16x16x32_bf16(a[m], b[n], acc[m][n], 0, 0, 0);
    }
  }

  float lp[NF];
  #pragma unroll
  for (int n = 0; n < NF; ++n)
    lp[n] = lowpass[n0 + wcol * WN + n * 16 + (lane & 15)];

  #pragma unroll
  for (int m = 0; m < MF; ++m) {
    #pragma unroll
    for (int r = 0; r < 4; ++r) {
      int rg = row0 + wrow * WM + m * 16 + (lane >> 4) * 4 + r;
      float psum = 0.f;
      #pragma unroll
      for (int n = 0; n < NF; ++n) {
        float v = fabsf(acc[m][n][r]);
        psum += v * lp[n];
        if (LAYER == 1) {
          int colg = n0 + wcol * WN + n * 16 + (lane & 15);
          size_t si = ((size_t)((rg >> 4) * 8 + j) * 16 + (rg & 15)) * ND + colg;
          Sout[si] = f2bf(v);
        }
      }
      psum += __shfl_xor(psum, 1);
      psum += __shfl_xor(psum, 2);
      psum += __shfl_xor(psum, 4);
      psum += __shfl_xor(psum, 8);
      if ((lane & 15) == 0) {
        int pidx;
        if (LAYER == 1) pidx = rg * 73 + 1 + j;
        else            pidx = ((rg >> 7) * 16 + (rg & 15)) * 73 + 9 + ((rg >> 4) & 7) * 8 + j;
        atomicAdd(&phi[pidx], psum);
      }
    }
  }
}

// ==== layer-2: 256x256 tile, 8 waves (128x64), register-double-buffered
//      half-K-tile pipeline with counted lgkmcnt (ds_read overlaps MFMA) ====

// load one half-K fragment set (kk = 0 or 1): 8 A-frags + 4 B-frags = 12 ds_read_b128
__device__ __forceinline__ void dsr_half(bf16x8 (&a)[8], bf16x8 (&b)[4],
                                         const unsigned short* Abase, const unsigned short* Bbase,
                                         int kk, int wrow, int wcol, int l15, int l4) {
  int q = kk * 4 + l4;
  #pragma unroll
  for (int m = 0; m < 8; ++m) {
    int r = wrow * 128 + m * 16 + l15;
    a[m] = *reinterpret_cast<const bf16x8*>(Abase + r * 64 + ((q ^ (r & 7)) << 3));
  }
  #pragma unroll
  for (int n = 0; n < 4; ++n) {
    int r = wcol * 64 + n * 16 + l15;
    b[n] = *reinterpret_cast<const bf16x8*>(Bbase + r * 64 + ((q ^ (r & 7)) << 3));
  }
}

__device__ __forceinline__ void mfma_all(f32x4 (&acc)[8][4], const bf16x8 (&a)[8],
                                         const bf16x8 (&b)[4]) {
  #pragma unroll
  for (int m = 0; m < 8; ++m)
    #pragma unroll
    for (int n = 0; n < 4; ++n)
      acc[m][n] = __builtin_amdgcn_mfma_f32_16x16x32_bf16(a[m], b[n], acc[m][n], 0, 0, 0);
}

// stage one full 256x64 K-tile of one operand (4 x gload_lds16 per thread, 512 thr)
__device__ __forceinline__ void stage_tile(const unsigned short* __restrict__ g, int grow0,
                                           int kofs, unsigned short* l, int tid) {
  #pragma unroll
  for (int p = 0; p < 4; ++p) {
    int c = p * 512 + tid;
    int r = c >> 3;
    int s = (c & 7) ^ (r & 7);
    gload_lds16(g + (size_t)(grow0 + r) * ND + kofs + (s << 3), l + (size_t)c * 8);
  }
}

#define SBAR()  __builtin_amdgcn_s_barrier()
#define SCHED0() __builtin_amdgcn_sched_barrier(0)
#define WAIT_LGKM(N) do { asm volatile("s_waitcnt lgkmcnt(" #N ")" ::: "memory"); SCHED0(); } while (0)
#define WAIT_VM(N) do { asm volatile("s_waitcnt vmcnt(" #N ")" ::: "memory"); SCHED0(); } while (0)

__global__ __launch_bounds__(512, 2)
void gemm_scat2(const unsigned short* __restrict__ A,
                const unsigned short* __restrict__ BT,
                const float* __restrict__ lowpass,
                float* __restrict__ phi) {
  extern __shared__ __align__(16) unsigned short smem[];
  unsigned short* As0 = smem;                 // [256][64] bf16, 32 KB each
  unsigned short* As1 = smem + 16384;
  unsigned short* Bs0 = smem + 32768;
  unsigned short* Bs1 = smem + 49152;

  const int tid  = threadIdx.x;
  const int lane = tid & 63;
  const int w    = tid >> 6;          // 8 waves: 2M x 4N
  const int wrow = w >> 2, wcol = w & 3;
  const int l15  = lane & 15, l4 = lane >> 4;

  // 256 blocks total: j = wg & 7 pins each psi^T[j] (2 MB) to one XCD's L2.
  int wg = blockIdx.x;
  const int j = wg & 7;
  const int t = wg >> 3;              // 0..31
  const int mtile = t & 7, ntile = t >> 3;
  const int row0 = mtile * 256, n0 = ntile * 256;
  const unsigned short* Bj = BT + (size_t)j * NNE;

  f32x4 acc[8][4] = {};
  bf16x8 a0[8], b0[4], a1[8], b1[4];  // two half-K fragment sets

  // prologue: stage K-tiles 0 and 1; gate tile0 only; preload set0 (tile0, kk0)
  stage_tile(A,  row0, 0,  As0, tid);
  stage_tile(Bj, n0,   0,  Bs0, tid);
  stage_tile(A,  row0, 64, As1, tid);
  stage_tile(Bj, n0,   64, Bs1, tid);
  WAIT_VM(8);
  SBAR();
  dsr_half(a0, b0, As0, Bs0, 0, wrow, wcol, l15, l4);
  SCHED0();

  #pragma unroll 1
  for (int i = 0; i < 16; ++i) {
    unsigned short* Ac = (i & 1) ? As1 : As0;
    unsigned short* Bc = (i & 1) ? Bs1 : Bs0;
    unsigned short* An = (i & 1) ? As0 : As1;
    unsigned short* Bn = (i & 1) ? Bs0 : Bs1;

    // --- step A: issue kk1 reads -> set1; MFMA set0 while they drain ---
    dsr_half(a1, b1, Ac, Bc, 1, wrow, wcol, l15, l4);
    SCHED0();
    WAIT_LGKM(12);                      // only the older 12 (set0) must be done
    __builtin_amdgcn_s_setprio(1);
    mfma_all(acc, a0, b0);
    __builtin_amdgcn_s_setprio(0);
    SCHED0();

    // --- step B: restage current buffer; issue next tile's kk0 reads; MFMA set1 ---
    WAIT_LGKM(0);                       // set1 ready; all of this wave's tile-i reads done
    SBAR();                             // every wave done reading tile i
    if (i < 14) {
      stage_tile(A,  row0, (i + 2) * 64, Ac, tid);   // overwrite tile i's buffer
      stage_tile(Bj, n0,   (i + 2) * 64, Bc, tid);
    }
    SCHED0();
    if (i < 15) {
      if (i < 14) { WAIT_VM(8); } else { WAIT_VM(0); }  // certify stage(i+1)
      SBAR();
      dsr_half(a0, b0, An, Bn, 0, wrow, wcol, l15, l4); // tile i+1, kk0 -> set0
      SCHED0();
    }
    __builtin_amdgcn_s_setprio(1);
    mfma_all(acc, a1, b1);              // overlaps set0's reads
    __builtin_amdgcn_s_setprio(0);
    SCHED0();
  }

  // epilogue: abs + lowpass dot + atomics into phi[...,9+k*8+j]
  float lp[4];
  #pragma unroll
  for (int n = 0; n < 4; ++n)
    lp[n] = lowpass[n0 + wcol * 64 + n * 16 + l15];

  #pragma unroll
  for (int m = 0; m < 8; ++m) {
    #pragma unroll
    for (int r = 0; r < 4; ++r) {
      int rg = row0 + wrow * 128 + m * 16 + l4 * 4 + r;
      float psum = 0.f;
      #pragma unroll
      for (int n = 0; n < 4; ++n)
        psum += fabsf(acc[m][n][r]) * lp[n];
      psum += __shfl_xor(psum, 1);
      psum += __shfl_xor(psum, 2);
      psum += __shfl_xor(psum, 4);
      psum += __shfl_xor(psum, 8);
      if (l15 == 0) {
        int pidx = ((rg >> 7) * 16 + (rg & 15)) * 73 + 9 + ((rg >> 4) & 7) * 8 + j;
        atomicAdd(&phi[pidx], psum);
      }
    }
  }
}

extern "C" void kernel_launch(void* const* d_in, const int* in_sizes, int n_in,
                              void* d_out, int out_size, void* d_ws, size_t ws_size,
                              hipStream_t stream) {
  (void)in_sizes; (void)n_in; (void)ws_size;
  const float* x       = (const float*)d_in[0];
  const float* psi     = (const float*)d_in[1];
  const float* lowpass = (const float*)d_in[2];
  float* phi = (float*)d_out;

  unsigned short* xb   = (unsigned short*)d_ws;                        // 512 KB
  unsigned short* psiT = (unsigned short*)((char*)d_ws + (1u << 20));  // 16 MB
  unsigned short* S1   = (unsigned short*)((char*)d_ws + (18u << 20)); // 4 MB

  hipMemsetAsync(d_out, 0, sizeof(float) * (size_t)out_size, stream);

  convert_phi0_kernel<<<256, 256, 0, stream>>>(x, lowpass, xb, phi);
  psi_transpose_kernel<<<8192, 256, 0, stream>>>(psi, psiT);

  // layer 1: M=256 rows, tiles 64x128 -> grid (8, 4, 8)
  gemm_scat<64, 128, 1><<<dim3(8, 4, 8), 256, 0, stream>>>(xb, psiT, lowpass, S1, phi);

  // layer 2: M=2048, 256x256 tiles, reg-dbuf half-K pipeline, 128 KiB LDS
  static int attr_set = 0;
  if (!attr_set) {
    hipFuncSetAttribute((const void*)gemm_scat2,
                        hipFuncAttributeMaxDynamicSharedMemorySize, 131072);
    attr_set = 1;
  }
  gemm_scat2<<<256, 512, 131072, stream>>>(S1, psiT, lowpass, phi);
}

// Round 10
// 72.703 us; speedup vs baseline: 1.5290x; 1.1450x over previous
//
#include <hip/hip_runtime.h>

#define ND 1024
#define NNE (ND*ND)

typedef __bf16 bf16x8 __attribute__((ext_vector_type(8)));
typedef float f32x4 __attribute__((ext_vector_type(4)));
typedef int i32x4 __attribute__((ext_vector_type(4)));
typedef int i32x8 __attribute__((ext_vector_type(8)));

__device__ __forceinline__ unsigned short f2bf(float f) {
  unsigned u = __float_as_uint(f);
  u += 0x7fffu + ((u >> 16) & 1u);
  return (unsigned short)(u >> 16);
}

__device__ __forceinline__ void gload_lds16(const void* g, void* l) {
  __builtin_amdgcn_global_load_lds(
      (const __attribute__((address_space(1))) void*)g,
      (__attribute__((address_space(3))) void*)l, 16, 0, 0);
}

// ---- fused: convert x row -> bf16, and phi[b,f,0] = x . lowpass ----
__global__ void convert_phi0_kernel(const float* __restrict__ x, const float* __restrict__ lp,
                                    unsigned short* __restrict__ xb, float* __restrict__ phi) {
  __shared__ float ws[4];
  int row = blockIdx.x;
  int t   = threadIdx.x;
  float4 v = reinterpret_cast<const float4*>(x + (size_t)row * ND)[t];
  float4 l = reinterpret_cast<const float4*>(lp)[t];
  ushort4 o;
  o.x = f2bf(v.x); o.y = f2bf(v.y); o.z = f2bf(v.z); o.w = f2bf(v.w);
  reinterpret_cast<ushort4*>(xb + (size_t)row * ND)[t] = o;
  float s = v.x * l.x + v.y * l.y + v.z * l.z + v.w * l.w;
  #pragma unroll
  for (int off = 32; off; off >>= 1) s += __shfl_xor(s, off);
  if ((t & 63) == 0) ws[t >> 6] = s;
  __syncthreads();
  if (t == 0) phi[row * 73] = ws[0] + ws[1] + ws[2] + ws[3];
}

// ---- transpose+convert psi: bf16 out[j][m][n] AND fp8 out8[j][m][n] = psi[j][n][m] ----
__global__ void psi_transpose_kernel(const float* __restrict__ psi,
                                     unsigned short* __restrict__ out,
                                     unsigned char* __restrict__ out8) {
  __shared__ float t[32][33];
  int blk = blockIdx.x;
  int j  = blk >> 10;
  int tn = (blk >> 5) & 31;
  int tm = blk & 31;
  const float* src = psi + ((size_t)j << 20) + (size_t)(tn << 5) * ND + (tm << 5);
  int r  = threadIdx.x >> 3;
  int c4 = (threadIdx.x & 7) << 2;
  float4 v = *reinterpret_cast<const float4*>(src + (size_t)r * ND + c4);
  t[r][c4 + 0] = v.x; t[r][c4 + 1] = v.y; t[r][c4 + 2] = v.z; t[r][c4 + 3] = v.w;
  __syncthreads();
  float f0 = t[c4 + 0][r], f1 = t[c4 + 1][r], f2 = t[c4 + 2][r], f3 = t[c4 + 3][r];
  ushort4 o;
  o.x = f2bf(f0); o.y = f2bf(f1); o.z = f2bf(f2); o.w = f2bf(f3);
  size_t base = ((size_t)j << 20) + (size_t)((tm << 5) + r) * ND + (tn << 5) + c4;
  *reinterpret_cast<ushort4*>(out + base) = o;
  int pk = __builtin_amdgcn_cvt_pk_fp8_f32(f0, f1, 0, false);
  pk = __builtin_amdgcn_cvt_pk_fp8_f32(f2, f3, pk, true);
  *reinterpret_cast<unsigned int*>(out8 + base) = (unsigned int)pk;
}

// ==== layer-1 GEMM (verified round-0 structure; epilogue now stores S1 as fp8) ====
template<int BM, int BN>
__global__ __launch_bounds__(256)
void gemm_scat(const unsigned short* __restrict__ A,
               const unsigned short* __restrict__ BT,
               const float* __restrict__ lowpass,
               unsigned char* __restrict__ Sout,
               float* __restrict__ phi) {
  constexpr int BK = 64;
  constexpr int WM = BM / 2, WN = BN / 2;
  constexpr int MF = WM / 16, NF = WN / 16;

  __shared__ __align__(16) unsigned short Asm[BM * BK];
  __shared__ __align__(16) unsigned short Bsm[BN * BK];

  const int tid  = threadIdx.x;
  const int lane = tid & 63;
  const int w    = tid >> 6;
  const int wrow = w >> 1, wcol = w & 1;

  const int j    = blockIdx.z;
  const int row0 = blockIdx.y * BM;
  const int n0   = blockIdx.x * BN;

  const unsigned short* Bj = BT + (size_t)j * NNE;

  f32x4 acc[MF][NF] = {};

  constexpr int ACH = BM * 8;
  constexpr int BCH = BN * 8;

  for (int k0 = 0; k0 < ND; k0 += BK) {
    __syncthreads();
    #pragma unroll
    for (int p = 0; p < ACH / 256; ++p) {
      int c = p * 256 + tid;
      int r = c >> 3;
      int s = (c & 7) ^ (r & 7);
      gload_lds16(A + (size_t)(row0 + r) * ND + k0 + s * 8, Asm + c * 8);
    }
    #pragma unroll
    for (int p = 0; p < BCH / 256; ++p) {
      int c = p * 256 + tid;
      int r = c >> 3;
      int s = (c & 7) ^ (r & 7);
      gload_lds16(Bj + (size_t)(n0 + r) * ND + k0 + s * 8, Bsm + c * 8);
    }
    __syncthreads();

    #pragma unroll
    for (int kk = 0; kk < 2; ++kk) {
      bf16x8 a[MF], b[NF];
      int srd = kk * 4 + (lane >> 4);
      #pragma unroll
      for (int m = 0; m < MF; ++m) {
        int r = wrow * WM + m * 16 + (lane & 15);
        a[m] = *reinterpret_cast<const bf16x8*>(&Asm[r * 64 + ((srd ^ (r & 7)) * 8)]);
      }
      #pragma unroll
      for (int n = 0; n < NF; ++n) {
        int r = wcol * WN + n * 16 + (lane & 15);
        b[n] = *reinterpret_cast<const bf16x8*>(&Bsm[r * 64 + ((srd ^ (r & 7)) * 8)]);
      }
      #pragma unroll
      for (int m = 0; m < MF; ++m)
        #pragma unroll
        for (int n = 0; n < NF; ++n)
          acc[m][n] = __builtin_amdgcn_mfma_f32_16x16x32_bf16(a[m], b[n], acc[m][n], 0, 0, 0);
    }
  }

  float lp[NF];
  #pragma unroll
  for (int n = 0; n < NF; ++n)
    lp[n] = lowpass[n0 + wcol * WN + n * 16 + (lane & 15)];

  #pragma unroll
  for (int m = 0; m < MF; ++m) {
    #pragma unroll
    for (int r = 0; r < 4; ++r) {
      int rg = row0 + wrow * WM + m * 16 + (lane >> 4) * 4 + r;
      float psum = 0.f;
      #pragma unroll
      for (int n = 0; n < NF; ++n) {
        float v = fabsf(acc[m][n][r]);
        psum += v * lp[n];
        int colg = n0 + wcol * WN + n * 16 + (lane & 15);
        size_t si = ((size_t)((rg >> 4) * 8 + j) * 16 + (rg & 15)) * ND + colg;
        int pk = __builtin_amdgcn_cvt_pk_fp8_f32(v, v, 0, false);
        Sout[si] = (unsigned char)(pk & 0xff);
      }
      psum += __shfl_xor(psum, 1);
      psum += __shfl_xor(psum, 2);
      psum += __shfl_xor(psum, 4);
      psum += __shfl_xor(psum, 8);
      if ((lane & 15) == 0) {
        int pidx = rg * 73 + 1 + j;
        atomicAdd(&phi[pidx], psum);
      }
    }
  }
}

// ==== layer-2: MX-fp8 (scale=1) 256x256 tile, 8 waves (128x64), BK=128,
//      round-5 4-phase rhythm (proven best schedule) ====

// one 32B fp8 fragment: two swizzled ds_read_b128 combined (k-order preserved)
__device__ __forceinline__ i32x8 dsr_frag8(const unsigned char* base, int r, int l4) {
  int s0 = l4 * 2;
  i32x4 lo = *reinterpret_cast<const i32x4*>(base + r * 128 + ((s0 ^ (r & 7)) << 4));
  i32x4 hi = *reinterpret_cast<const i32x4*>(base + r * 128 + (((s0 + 1) ^ (r & 7)) << 4));
  return __builtin_shufflevector(lo, hi, 0, 1, 2, 3, 4, 5, 6, 7);
}

template<int MH>
__device__ __forceinline__ void dsr_a8(i32x8 (&dst)[4], const unsigned char* base,
                                       int wrow, int l15, int l4) {
  #pragma unroll
  for (int m = 0; m < 4; ++m)
    dst[m] = dsr_frag8(base, wrow * 128 + (MH + m) * 16 + l15, l4);
}

template<int NL>
__device__ __forceinline__ void dsr_b8(i32x8 (&dst)[2], const unsigned char* base,
                                       int wcol, int l15, int l4) {
  #pragma unroll
  for (int n = 0; n < 2; ++n)
    dst[n] = dsr_frag8(base, wcol * 64 + (NL + n) * 16 + l15, l4);
}

template<int MH, int NL>
__device__ __forceinline__ void mfma_q8(f32x4 (&acc)[8][4], const i32x8 (&a)[4],
                                        const i32x8 (&b)[2]) {
  #pragma unroll
  for (int m = 0; m < 4; ++m)
    #pragma unroll
    for (int n = 0; n < 2; ++n)
      acc[MH + m][NL + n] = __builtin_amdgcn_mfma_scale_f32_16x16x128_f8f6f4(
          a[m], b[n], acc[MH + m][NL + n], 0, 0, 0, 0x7f7f7f7f, 0, 0x7f7f7f7f);
}

// stage one 256x128B fp8 K-tile (2048 chunks, 4 per thread at 512 thr)
__device__ __forceinline__ void stage_tile8(const unsigned char* __restrict__ g, int grow0,
                                            int kofs, unsigned char* l, int tid) {
  #pragma unroll
  for (int p = 0; p < 4; ++p) {
    int c = p * 512 + tid;
    int r = c >> 3;
    int s = (c & 7) ^ (r & 7);
    gload_lds16(g + (size_t)(grow0 + r) * ND + kofs + (s << 4), l + (size_t)c * 16);
  }
}

#define SBAR()  __builtin_amdgcn_s_barrier()
#define SCHED0() __builtin_amdgcn_sched_barrier(0)
#define WAIT_LGKM0() do { asm volatile("s_waitcnt lgkmcnt(0)" ::: "memory"); SCHED0(); } while (0)
#define WAIT_VM0() do { asm volatile("s_waitcnt vmcnt(0)" ::: "memory"); SCHED0(); } while (0)
#define PRIO_MFMA(stmt) do { __builtin_amdgcn_s_setprio(1); stmt; __builtin_amdgcn_s_setprio(0); SCHED0(); } while (0)

__global__ __launch_bounds__(512, 2)
void gemm_scat2(const unsigned char* __restrict__ A,
                const unsigned char* __restrict__ BT,
                const float* __restrict__ lowpass,
                float* __restrict__ phi) {
  extern __shared__ __align__(16) unsigned char smem[];
  unsigned char* As0 = smem;                 // [256][128] fp8, 32 KB each
  unsigned char* As1 = smem + 32768;
  unsigned char* Bs0 = smem + 65536;
  unsigned char* Bs1 = smem + 98304;

  const int tid  = threadIdx.x;
  const int lane = tid & 63;
  const int w    = tid >> 6;          // 8 waves: 2M x 4N
  const int wrow = w >> 2, wcol = w & 3;
  const int l15  = lane & 15, l4 = lane >> 4;

  int wg = blockIdx.x;
  const int j = wg & 7;               // j per XCD
  const int t = wg >> 3;              // 0..31
  const int mtile = t & 7, ntile = t >> 3;
  const int row0 = mtile * 256, n0 = ntile * 256;
  const unsigned char* Bj = BT + (size_t)j * NNE;

  f32x4 acc[8][4] = {};
  i32x8 aX[4], bL[2], bH[2];

  // prologue: stage K-tile 0
  stage_tile8(A,  row0, 0, As0, tid);
  stage_tile8(Bj, n0,   0, Bs0, tid);
  WAIT_VM0();
  SBAR();

  #pragma unroll 1
  for (int i = 0; i < 8; ++i) {
    const unsigned char* Ac = (i & 1) ? As1 : As0;
    const unsigned char* Bc = (i & 1) ? Bs1 : Bs0;
    unsigned char* An = (i & 1) ? As0 : As1;
    unsigned char* Bn = (i & 1) ? Bs0 : Bs1;
    const bool st = (i < 7);
    const int knext = (i + 1) * 128;

    // P0: dsr aLo + bLo; stage next A; MFMA Q(0,0)
    dsr_a8<0>(aX, Ac, wrow, l15, l4);
    dsr_b8<0>(bL, Bc, wcol, l15, l4);
    if (st) stage_tile8(A, row0, knext, An, tid);
    SCHED0();
    SBAR(); WAIT_LGKM0();
    PRIO_MFMA((mfma_q8<0,0>(acc, aX, bL)));
    SBAR();
    // P1: dsr bHi; stage next B; MFMA Q(0,2)
    dsr_b8<2>(bH, Bc, wcol, l15, l4);
    if (st) stage_tile8(Bj, n0, knext, Bn, tid);
    SCHED0();
    SBAR(); WAIT_LGKM0();
    PRIO_MFMA((mfma_q8<0,2>(acc, aX, bH)));
    SBAR();
    // P2: dsr aHi (overwrite aX); MFMA Q(4,0)
    dsr_a8<4>(aX, Ac, wrow, l15, l4);
    SBAR(); WAIT_LGKM0();
    PRIO_MFMA((mfma_q8<4,0>(acc, aX, bL)));
    SBAR();
    // P3: MFMA Q(4,2); gate next tile's loads
    PRIO_MFMA((mfma_q8<4,2>(acc, aX, bH)));
    WAIT_VM0();
    SBAR();
  }

  // epilogue: abs + lowpass dot + atomics into phi[...,9+k*8+j]
  float lp[4];
  #pragma unroll
  for (int n = 0; n < 4; ++n)
    lp[n] = lowpass[n0 + wcol * 64 + n * 16 + l15];

  #pragma unroll
  for (int m = 0; m < 8; ++m) {
    #pragma unroll
    for (int r = 0; r < 4; ++r) {
      int rg = row0 + wrow * 128 + m * 16 + l4 * 4 + r;
      float psum = 0.f;
      #pragma unroll
      for (int n = 0; n < 4; ++n)
        psum += fabsf(acc[m][n][r]) * lp[n];
      psum += __shfl_xor(psum, 1);
      psum += __shfl_xor(psum, 2);
      psum += __shfl_xor(psum, 4);
      psum += __shfl_xor(psum, 8);
      if (l15 == 0) {
        int pidx = ((rg >> 7) * 16 + (rg & 15)) * 73 + 9 + ((rg >> 4) & 7) * 8 + j;
        atomicAdd(&phi[pidx], psum);
      }
    }
  }
}

extern "C" void kernel_launch(void* const* d_in, const int* in_sizes, int n_in,
                              void* d_out, int out_size, void* d_ws, size_t ws_size,
                              hipStream_t stream) {
  (void)in_sizes; (void)n_in; (void)ws_size;
  const float* x       = (const float*)d_in[0];
  const float* psi     = (const float*)d_in[1];
  const float* lowpass = (const float*)d_in[2];
  float* phi = (float*)d_out;

  unsigned short* xb    = (unsigned short*)d_ws;                        // 512 KB
  unsigned short* psiT  = (unsigned short*)((char*)d_ws + (1u  << 20)); // 16 MB  (bf16, layer-1)
  unsigned char*  S1f8  = (unsigned char*) ((char*)d_ws + (17u << 20)); // 2 MB   (fp8, layer-2 A)
  unsigned char*  psiT8 = (unsigned char*) ((char*)d_ws + (19u << 20)); // 8 MB   (fp8, layer-2 B)

  hipMemsetAsync(d_out, 0, sizeof(float) * (size_t)out_size, stream);

  convert_phi0_kernel<<<256, 256, 0, stream>>>(x, lowpass, xb, phi);
  psi_transpose_kernel<<<8192, 256, 0, stream>>>(psi, psiT, psiT8);

  // layer 1: bf16 MFMA, M=256, tiles 64x128 -> grid (8, 4, 8); stores S1 as fp8
  gemm_scat<64, 128><<<dim3(8, 4, 8), 256, 0, stream>>>(xb, psiT, lowpass, S1f8, phi);

  // layer 2: MX-fp8 (scale=1) 16x16x128 MFMA, 256x256 tiles, 128 KiB LDS, 256 blocks
  static int attr_set = 0;
  if (!attr_set) {
    hipFuncSetAttribute((const void*)gemm_scat2,
                        hipFuncAttributeMaxDynamicSharedMemorySize, 131072);
    attr_set = 1;
  }
  gemm_scat2<<<256, 512, 131072, stream>>>(S1f8, psiT8, lowpass, phi);
}